// Round 1
// baseline (691.763 us; speedup 1.0000x reference)
//
#include <hip/hip_runtime.h>
#include <math.h>

#define IN_DIM 128
#define HID 64

// ---------------- degree: count edges per target node --------------------
__global__ void k_deg(const int* __restrict__ col, int* __restrict__ cnt, int E) {
    int e = blockIdx.x * blockDim.x + threadIdx.x;
    if (e < E) atomicAdd(&cnt[col[e]], 1);
}

// dis[i] = rsqrt(deg[i])  with deg = count + 1 (self-loop). In-place int->float.
__global__ void k_dis(float* __restrict__ buf, int n) {
    int i = blockIdx.x * blockDim.x + threadIdx.x;
    if (i < n) {
        int c = ((const int*)buf)[i];
        buf[i] = rsqrtf((float)(c + 1));
    }
}

// ---------------- h1 = x @ W1   [n,128]@[128,64] -------------------------
// one wave per node; W1 staged in LDS once per block (32 KB)
__global__ void __launch_bounds__(256) k_gemm1(const float* __restrict__ x,
                                               const float* __restrict__ W1,
                                               float* __restrict__ h1, int n) {
    __shared__ float wlds[IN_DIM * HID];   // 32 KB
    __shared__ float xs[4][IN_DIM];        // 2 KB
    int t = threadIdx.x;
    for (int i = t; i < IN_DIM * HID; i += 256) wlds[i] = W1[i];

    int wave = t >> 6, lane = t & 63;
    int node = blockIdx.x * 4 + wave;
    bool active = node < n;
    if (active) {
        xs[wave][lane]      = x[node * IN_DIM + lane];
        xs[wave][lane + 64] = x[node * IN_DIM + lane + 64];
    }
    __syncthreads();
    if (!active) return;

    float acc = 0.f;
#pragma unroll 8
    for (int k = 0; k < IN_DIM; ++k)
        acc = fmaf(xs[wave][k], wlds[k * HID + lane], acc);
    h1[node * HID + lane] = acc;
}

// ---------------- scatter layer 1: one wave per edge ---------------------
__global__ void k_scatter1(const int* __restrict__ row, const int* __restrict__ col,
                           const float* __restrict__ dis, const float* __restrict__ h1,
                           float* __restrict__ agg1, int E) {
    long long gid = (long long)blockIdx.x * blockDim.x + threadIdx.x;
    int e = (int)(gid >> 6);
    int lane = (int)(gid & 63);
    if (e >= E) return;
    int r = row[e], c = col[e];
    float nrm = dis[r] * dis[c];
    float v = h1[(long long)r * HID + lane] * nrm;
    atomicAdd(&agg1[(long long)c * HID + lane], v);
}

// ------- fused: tanh(agg1 + selfloop + b1) then @W2 -> emb2 [n,2] --------
// one wave per node; lane j owns hidden feature j; cross-lane reduce for W2
__global__ void k_act_emb2(const float* __restrict__ agg1, const float* __restrict__ h1,
                           const float* __restrict__ dis, const float* __restrict__ b1,
                           const float* __restrict__ W2, float* __restrict__ emb2, int n) {
    long long gid = (long long)blockIdx.x * blockDim.x + threadIdx.x;
    int node = (int)(gid >> 6), lane = (int)(gid & 63);
    if (node >= n) return;
    float d = dis[node];
    float v = tanhf(agg1[(long long)node * HID + lane]
                    + h1[(long long)node * HID + lane] * d * d + b1[lane]);
    float s0 = v * W2[lane * 2 + 0];
    float s1 = v * W2[lane * 2 + 1];
    for (int off = 32; off; off >>= 1) {
        s0 += __shfl_xor(s0, off);
        s1 += __shfl_xor(s1, off);
    }
    if (lane == 0) {
        emb2[node * 2 + 0] = s0;
        emb2[node * 2 + 1] = s1;
    }
}

// ---------------- scatter layer 2: one thread per edge -------------------
__global__ void k_scatter2(const int* __restrict__ row, const int* __restrict__ col,
                           const float* __restrict__ dis, const float* __restrict__ emb2,
                           float* __restrict__ agg2, int E) {
    int e = blockIdx.x * blockDim.x + threadIdx.x;
    if (e >= E) return;
    int r = row[e], c = col[e];
    float nrm = dis[r] * dis[c];
    float2 v = *(const float2*)&emb2[r * 2];
    atomicAdd(&agg2[c * 2 + 0], v.x * nrm);
    atomicAdd(&agg2[c * 2 + 1], v.y * nrm);
}

// ---------------- epilogue: tanh, classifier, sigmoid --------------------
__global__ void k_final(const float* __restrict__ agg2, const float* __restrict__ emb2,
                        const float* __restrict__ dis, const float* __restrict__ b2,
                        const float* __restrict__ Wc, const float* __restrict__ bc,
                        float* __restrict__ out, int n) {
    int i = blockIdx.x * blockDim.x + threadIdx.x;
    if (i >= n) return;
    float d = dis[i], d2 = d * d;
    float2 me = *(const float2*)&emb2[i * 2];
    float e0 = tanhf(agg2[i * 2 + 0] + me.x * d2 + b2[0]);
    float e1 = tanhf(agg2[i * 2 + 1] + me.y * d2 + b2[1]);
    float z = e0 * Wc[0] + e1 * Wc[1] + bc[0];
    out[i] = 1.f / (1.f + expf(-z));
}

extern "C" void kernel_launch(void* const* d_in, const int* in_sizes, int n_in,
                              void* d_out, int out_size, void* d_ws, size_t ws_size,
                              hipStream_t stream) {
    const float* x  = (const float*)d_in[0];
    const int*   ei = (const int*)d_in[1];   // [2, E]
    const float* W1 = (const float*)d_in[2];
    const float* b1 = (const float*)d_in[3];
    const float* W2 = (const float*)d_in[4];
    const float* b2 = (const float*)d_in[5];
    const float* Wc = (const float*)d_in[6];
    const float* bc = (const float*)d_in[7];

    const int n = in_sizes[0] / IN_DIM;
    const int E = in_sizes[1] / 2;
    const int* row = ei;
    const int* col = ei + E;

    // workspace layout (floats)
    float* dis  = (float*)d_ws;          // n      (int counts, then dis)
    float* h1   = dis + n;               // n*64
    float* agg1 = h1 + (size_t)n * HID;  // n*64
    float* emb2 = agg1 + (size_t)n * HID;// n*2
    float* agg2 = emb2 + (size_t)n * 2;  // n*2

    hipMemsetAsync(dis,  0, (size_t)n * sizeof(float), stream);
    hipMemsetAsync(agg1, 0, (size_t)n * HID * sizeof(float), stream);
    hipMemsetAsync(agg2, 0, (size_t)n * 2 * sizeof(float), stream);

    k_deg<<<(E + 255) / 256, 256, 0, stream>>>(col, (int*)dis, E);
    k_dis<<<(n + 255) / 256, 256, 0, stream>>>(dis, n);
    k_gemm1<<<(n + 3) / 4, 256, 0, stream>>>(x, W1, h1, n);
    k_scatter1<<<(int)(((long long)E * 64 + 255) / 256), 256, 0, stream>>>(row, col, dis, h1, agg1, E);
    k_act_emb2<<<(n + 3) / 4, 256, 0, stream>>>(agg1, h1, dis, b1, W2, emb2, n);
    k_scatter2<<<(E + 255) / 256, 256, 0, stream>>>(row, col, dis, emb2, agg2, E);
    k_final<<<(n + 255) / 256, 256, 0, stream>>>(agg2, emb2, dis, b2, Wc, bc, (float*)d_out, n);
}

// Round 2
// 443.663 us; speedup vs baseline: 1.5592x; 1.5592x over previous
//
#include <hip/hip_runtime.h>
#include <math.h>

#define IN_DIM 128
#define HID 64
#define SCAN_BLK 1024

// ---------------- degree count (indegree over col) -----------------------
__global__ void k_deg(const int* __restrict__ col, int* __restrict__ cnt, int E) {
    int e = blockIdx.x * blockDim.x + threadIdx.x;
    if (e < E) atomicAdd(&cnt[col[e]], 1);
}

// dis[i] = rsqrt(cnt[i] + 1)   (+1 = self-loop)
__global__ void k_dis(const int* __restrict__ cnt, float* __restrict__ dis, int n) {
    int i = blockIdx.x * blockDim.x + threadIdx.x;
    if (i < n) dis[i] = rsqrtf((float)(cnt[i] + 1));
}

// ---------------- 3-phase exclusive scan of cnt -> ptr -------------------
__global__ void __launch_bounds__(SCAN_BLK) k_scanA(const int* __restrict__ cnt,
                                                    int* __restrict__ ptr,
                                                    int* __restrict__ bsum, int n) {
    __shared__ int s[SCAN_BLK];
    int tid = threadIdx.x;
    int i = blockIdx.x * SCAN_BLK + tid;
    int v = (i < n) ? cnt[i] : 0;
    s[tid] = v;
    __syncthreads();
    for (int off = 1; off < SCAN_BLK; off <<= 1) {
        int t = (tid >= off) ? s[tid - off] : 0;
        __syncthreads();
        s[tid] += t;
        __syncthreads();
    }
    if (i < n) ptr[i] = s[tid] - v;             // block-local exclusive
    if (tid == SCAN_BLK - 1) bsum[blockIdx.x] = s[tid];
}

__global__ void k_scanB(int* __restrict__ bsum, int nb) {
    __shared__ int s[128];
    int tid = threadIdx.x;
    int v = (tid < nb) ? bsum[tid] : 0;
    s[tid] = v;
    __syncthreads();
    for (int off = 1; off < 128; off <<= 1) {
        int t = (tid >= off) ? s[tid - off] : 0;
        __syncthreads();
        s[tid] += t;
        __syncthreads();
    }
    if (tid < nb) bsum[tid] = s[tid] - v;       // exclusive block offsets
}

__global__ void __launch_bounds__(SCAN_BLK) k_scanC(int* __restrict__ ptr,
                                                    int* __restrict__ cursor,
                                                    const int* __restrict__ bsum,
                                                    int n, int E) {
    int i = blockIdx.x * SCAN_BLK + threadIdx.x;
    if (i < n) {
        int p = ptr[i] + bsum[blockIdx.x];
        ptr[i] = p;
        cursor[i] = p;
        if (i == n - 1) ptr[n] = E;
    }
}

// ---------------- CSR position-scatter: src + precomputed norm -----------
__global__ void k_build(const int* __restrict__ row, const int* __restrict__ col,
                        const float* __restrict__ dis, int* __restrict__ cursor,
                        int* __restrict__ src, float* __restrict__ nrm, int E) {
    int e = blockIdx.x * blockDim.x + threadIdx.x;
    if (e >= E) return;
    int r = row[e], c = col[e];
    int p = atomicAdd(&cursor[c], 1);
    src[p] = r;
    nrm[p] = dis[r] * dis[c];
}

// ---------------- h1 = x @ W1   [n,128]@[128,64] -------------------------
__global__ void __launch_bounds__(256) k_gemm1(const float* __restrict__ x,
                                               const float* __restrict__ W1,
                                               float* __restrict__ h1, int n) {
    __shared__ float wlds[IN_DIM * HID];   // 32 KB
    __shared__ float xs[4][IN_DIM];        // 2 KB
    int t = threadIdx.x;
    for (int i = t; i < IN_DIM * HID; i += 256) wlds[i] = W1[i];

    int wave = t >> 6, lane = t & 63;
    int node = blockIdx.x * 4 + wave;
    bool active = node < n;
    if (active) {
        xs[wave][lane]      = x[node * IN_DIM + lane];
        xs[wave][lane + 64] = x[node * IN_DIM + lane + 64];
    }
    __syncthreads();
    if (!active) return;

    float acc = 0.f;
#pragma unroll 8
    for (int k = 0; k < IN_DIM; ++k)
        acc = fmaf(xs[wave][k], wlds[k * HID + lane], acc);
    h1[(size_t)node * HID + lane] = acc;
}

// ---- fused: gather layer-1 agg + self-loop + b1 + tanh + @W2 -> emb2 ----
// one wave per node; lane owns hidden feature; cross-lane reduce for W2
__global__ void __launch_bounds__(256) k_gather1(const int* __restrict__ ptr,
                                                 const int* __restrict__ src,
                                                 const float* __restrict__ nrm,
                                                 const float* __restrict__ h1,
                                                 const float* __restrict__ dis,
                                                 const float* __restrict__ b1,
                                                 const float* __restrict__ W2,
                                                 float* __restrict__ emb2, int n) {
    int t = threadIdx.x;
    int wave = t >> 6, lane = t & 63;
    int node = blockIdx.x * 4 + wave;
    if (node >= n) return;
    int p0 = ptr[node], p1 = ptr[node + 1];
    float d = dis[node];
    float acc = h1[(size_t)node * HID + lane] * d * d;   // self-loop
    for (int p = p0; p < p1; ++p) {
        int r = src[p];
        float w = nrm[p];
        acc = fmaf(h1[(size_t)r * HID + lane], w, acc);
    }
    float v = tanhf(acc + b1[lane]);
    float s0 = v * W2[lane * 2 + 0];
    float s1 = v * W2[lane * 2 + 1];
    for (int off = 32; off; off >>= 1) {
        s0 += __shfl_xor(s0, off);
        s1 += __shfl_xor(s1, off);
    }
    if (lane == 0) {
        emb2[node * 2 + 0] = s0;
        emb2[node * 2 + 1] = s1;
    }
}

// ---- fused: gather layer-2 agg + tanh + classifier + sigmoid -> out -----
// one thread per node (2-wide features, ~16 edges avg)
__global__ void k_gather2(const int* __restrict__ ptr, const int* __restrict__ src,
                          const float* __restrict__ nrm, const float* __restrict__ emb2,
                          const float* __restrict__ dis, const float* __restrict__ b2,
                          const float* __restrict__ Wc, const float* __restrict__ bc,
                          float* __restrict__ out, int n) {
    int i = blockIdx.x * blockDim.x + threadIdx.x;
    if (i >= n) return;
    int p0 = ptr[i], p1 = ptr[i + 1];
    float d = dis[i];
    float2 me = *(const float2*)&emb2[i * 2];
    float a0 = me.x * d * d, a1 = me.y * d * d;          // self-loop
    for (int p = p0; p < p1; ++p) {
        int r = src[p];
        float w = nrm[p];
        float2 v = *(const float2*)&emb2[r * 2];
        a0 = fmaf(v.x, w, a0);
        a1 = fmaf(v.y, w, a1);
    }
    float e0 = tanhf(a0 + b2[0]);
    float e1 = tanhf(a1 + b2[1]);
    float z = fmaf(e0, Wc[0], fmaf(e1, Wc[1], bc[0]));
    out[i] = 1.f / (1.f + expf(-z));
}

extern "C" void kernel_launch(void* const* d_in, const int* in_sizes, int n_in,
                              void* d_out, int out_size, void* d_ws, size_t ws_size,
                              hipStream_t stream) {
    const float* x  = (const float*)d_in[0];
    const int*   ei = (const int*)d_in[1];   // [2, E] as int32
    const float* W1 = (const float*)d_in[2];
    const float* b1 = (const float*)d_in[3];
    const float* W2 = (const float*)d_in[4];
    const float* b2 = (const float*)d_in[5];
    const float* Wc = (const float*)d_in[6];
    const float* bc = (const float*)d_in[7];

    const int n = in_sizes[0] / IN_DIM;
    const int E = in_sizes[1] / 2;
    const int* row = ei;
    const int* col = ei + E;

    const int nblk = (n + SCAN_BLK - 1) / SCAN_BLK;   // 98 for n=100000 (<=128)

    // workspace layout
    char* w = (char*)d_ws;
    int*   cnt    = (int*)w;                 w += (size_t)n * 4;
    float* dis    = (float*)w;               w += (size_t)n * 4;
    int*   ptr    = (int*)w;                 w += (size_t)(n + 1) * 4;
    int*   cursor = (int*)w;                 w += (size_t)n * 4;
    int*   bsum   = (int*)w;                 w += 128 * 4;
    int*   src    = (int*)w;                 w += (size_t)E * 4;
    float* nrm    = (float*)w;               w += (size_t)E * 4;
    float* h1     = (float*)w;               w += (size_t)n * HID * 4;
    float* emb2   = (float*)w;               w += (size_t)n * 2 * 4;

    hipMemsetAsync(cnt, 0, (size_t)n * 4, stream);

    k_deg  <<<(E + 255) / 256, 256, 0, stream>>>(col, cnt, E);
    k_dis  <<<(n + 255) / 256, 256, 0, stream>>>(cnt, dis, n);
    k_scanA<<<nblk, SCAN_BLK, 0, stream>>>(cnt, ptr, bsum, n);
    k_scanB<<<1, 128, 0, stream>>>(bsum, nblk);
    k_scanC<<<nblk, SCAN_BLK, 0, stream>>>(ptr, cursor, bsum, n, E);
    k_build<<<(E + 255) / 256, 256, 0, stream>>>(row, col, dis, cursor, src, nrm, E);
    k_gemm1<<<(n + 3) / 4, 256, 0, stream>>>(x, W1, h1, n);
    k_gather1<<<(n + 3) / 4, 256, 0, stream>>>(ptr, src, nrm, h1, dis, b1, W2, emb2, n);
    k_gather2<<<(n + 255) / 256, 256, 0, stream>>>(ptr, src, nrm, emb2, dis, b2, Wc, bc,
                                                   (float*)d_out, n);
}

// Round 3
// 390.369 us; speedup vs baseline: 1.7721x; 1.1365x over previous
//
#include <hip/hip_runtime.h>
#include <math.h>

#define IN_DIM 128
#define HID 64
#define SCAN_BLK 1024

typedef __attribute__((ext_vector_type(8))) short bf16x8;
typedef __attribute__((ext_vector_type(4))) float f32x4;

static __device__ inline short f2bf(float f) {
    unsigned u = __float_as_uint(f);
    u += 0x7fff + ((u >> 16) & 1);          // RNE
    return (short)(u >> 16);
}

// ---------------- degree count (indegree over col) -----------------------
__global__ void k_deg(const int* __restrict__ col, int* __restrict__ cnt, int E) {
    int e = blockIdx.x * blockDim.x + threadIdx.x;
    if (e < E) atomicAdd(&cnt[col[e]], 1);
}

__global__ void k_dis(const int* __restrict__ cnt, float* __restrict__ dis, int n) {
    int i = blockIdx.x * blockDim.x + threadIdx.x;
    if (i < n) dis[i] = rsqrtf((float)(cnt[i] + 1));
}

// ------- pack W1 [128][64] f32 -> bf16 MFMA B-fragment order -------------
// frag idx = (kc*4+fb); lane 0..63; elem i 0..7
// B element (k = kc*32 + (lane>>4)*8 + i, f = fb*16 + (lane&15))
__global__ void k_packW(const float* __restrict__ W1, ushort* __restrict__ W1p) {
    int idx = blockIdx.x * 256 + threadIdx.x;        // 0..8191
    int i = idx & 7, lane = (idx >> 3) & 63, fb = (idx >> 9) & 3, kc = (idx >> 11) & 3;
    int k = kc * 32 + (lane >> 4) * 8 + i;
    int f = fb * 16 + (lane & 15);
    W1p[idx] = (ushort)f2bf(W1[k * HID + f]);
}

// ---------------- 3-phase exclusive scan of cnt -> ptr -------------------
__global__ void __launch_bounds__(SCAN_BLK) k_scanA(const int* __restrict__ cnt,
                                                    int* __restrict__ ptr,
                                                    int* __restrict__ bsum, int n) {
    __shared__ int s[SCAN_BLK];
    int tid = threadIdx.x;
    int i = blockIdx.x * SCAN_BLK + tid;
    int v = (i < n) ? cnt[i] : 0;
    s[tid] = v;
    __syncthreads();
    for (int off = 1; off < SCAN_BLK; off <<= 1) {
        int t = (tid >= off) ? s[tid - off] : 0;
        __syncthreads();
        s[tid] += t;
        __syncthreads();
    }
    if (i < n) ptr[i] = s[tid] - v;
    if (tid == SCAN_BLK - 1) bsum[blockIdx.x] = s[tid];
}

__global__ void k_scanB(int* __restrict__ bsum, int nb) {
    __shared__ int s[128];
    int tid = threadIdx.x;
    int v = (tid < nb) ? bsum[tid] : 0;
    s[tid] = v;
    __syncthreads();
    for (int off = 1; off < 128; off <<= 1) {
        int t = (tid >= off) ? s[tid - off] : 0;
        __syncthreads();
        s[tid] += t;
        __syncthreads();
    }
    if (tid < nb) bsum[tid] = s[tid] - v;
}

__global__ void __launch_bounds__(SCAN_BLK) k_scanC(int* __restrict__ ptr,
                                                    int* __restrict__ cursor,
                                                    const int* __restrict__ bsum,
                                                    int n, int E) {
    int i = blockIdx.x * SCAN_BLK + threadIdx.x;
    if (i < n) {
        int p = ptr[i] + bsum[blockIdx.x];
        ptr[i] = p;
        cursor[i] = p;
        if (i == n - 1) ptr[n] = E;
    }
}

// ---------------- CSR position-scatter: src only -------------------------
__global__ void k_build(const int* __restrict__ row, const int* __restrict__ col,
                        int* __restrict__ cursor, int* __restrict__ src, int E) {
    int e = blockIdx.x * blockDim.x + threadIdx.x;
    if (e >= E) return;
    int r = row[e], c = col[e];
    int p = atomicAdd(&cursor[c], 1);
    src[p] = r;
}

// ------- h1s = (x @ W1) * dis[node]  via bf16 MFMA, fp16 output ----------
// block = 256 threads = 4 waves; each wave: 16 nodes x 64 feats
__global__ void __launch_bounds__(256) k_gemm1(const float* __restrict__ x,
                                               const ushort* __restrict__ W1p,
                                               const float* __restrict__ dis,
                                               _Float16* __restrict__ h1s, int n) {
    int t = threadIdx.x, wave = t >> 6, lane = t & 63;
    int nb = blockIdx.x * 64 + wave * 16;
    int arow = nb + (lane & 15);            // A: row = lane&15
    int g = lane >> 4;                      // k-group
    const bf16x8* Wp = (const bf16x8*)W1p;

    f32x4 acc0 = {0.f, 0.f, 0.f, 0.f}, acc1 = acc0, acc2 = acc0, acc3 = acc0;

#pragma unroll
    for (int kc = 0; kc < 4; ++kc) {
        bf16x8 a;
        if (arow < n) {
            const float4* xp = (const float4*)(x + (size_t)arow * IN_DIM + kc * 32 + g * 8);
            float4 x0 = xp[0], x1 = xp[1];
            a[0] = f2bf(x0.x); a[1] = f2bf(x0.y); a[2] = f2bf(x0.z); a[3] = f2bf(x0.w);
            a[4] = f2bf(x1.x); a[5] = f2bf(x1.y); a[6] = f2bf(x1.z); a[7] = f2bf(x1.w);
        } else {
            for (int i = 0; i < 8; ++i) a[i] = 0;
        }
        acc0 = __builtin_amdgcn_mfma_f32_16x16x32_bf16(a, Wp[(kc * 4 + 0) * 64 + lane], acc0, 0, 0, 0);
        acc1 = __builtin_amdgcn_mfma_f32_16x16x32_bf16(a, Wp[(kc * 4 + 1) * 64 + lane], acc1, 0, 0, 0);
        acc2 = __builtin_amdgcn_mfma_f32_16x16x32_bf16(a, Wp[(kc * 4 + 2) * 64 + lane], acc2, 0, 0, 0);
        acc3 = __builtin_amdgcn_mfma_f32_16x16x32_bf16(a, Wp[(kc * 4 + 3) * 64 + lane], acc3, 0, 0, 0);
    }

    // D: col = lane&15, row = (lane>>4)*4 + reg
    int c = lane & 15, rbase = g * 4;
    float dn[4];
    int nd[4];
#pragma unroll
    for (int r = 0; r < 4; ++r) {
        nd[r] = nb + rbase + r;
        dn[r] = (nd[r] < n) ? dis[nd[r]] : 0.f;
    }
#define EPI(FB, ACC)                                                          \
    {                                                                         \
        int f = FB * 16 + c;                                                  \
        _Pragma("unroll") for (int r = 0; r < 4; ++r) {                       \
            if (nd[r] < n)                                                    \
                h1s[(size_t)nd[r] * HID + f] = (_Float16)(ACC[r] * dn[r]);    \
        }                                                                     \
    }
    EPI(0, acc0) EPI(1, acc1) EPI(2, acc2) EPI(3, acc3)
#undef EPI
}

// ---- gather layer-1: agg = dis_c*(sum h1s[r] + h1s[c]); tanh; @W2 -------
__global__ void __launch_bounds__(256) k_gather1(const int* __restrict__ ptr,
                                                 const int* __restrict__ src,
                                                 const _Float16* __restrict__ h1s,
                                                 const float* __restrict__ dis,
                                                 const float* __restrict__ b1,
                                                 const float* __restrict__ W2,
                                                 float* __restrict__ es, int n) {
    int t = threadIdx.x, wave = t >> 6, lane = t & 63;
    int node = blockIdx.x * 4 + wave;
    if (node >= n) return;
    int p0 = ptr[node], p1 = ptr[node + 1];
    float acc = (float)h1s[(size_t)node * HID + lane];   // self-loop term
    for (int p = p0; p < p1; ++p) {
        int r = src[p];
        acc += (float)h1s[(size_t)r * HID + lane];
    }
    float d = dis[node];
    float v = tanhf(fmaf(acc, d, b1[lane]));
    float s0 = v * W2[lane * 2 + 0];
    float s1 = v * W2[lane * 2 + 1];
    for (int off = 32; off; off >>= 1) {
        s0 += __shfl_xor(s0, off);
        s1 += __shfl_xor(s1, off);
    }
    if (lane == 0) {
        es[node * 2 + 0] = s0 * d;     // pre-scaled by dis for layer-2 gather
        es[node * 2 + 1] = s1 * d;
    }
}

// ---- gather layer-2 + tanh + classifier + sigmoid -----------------------
__global__ void k_gather2(const int* __restrict__ ptr, const int* __restrict__ src,
                          const float* __restrict__ es, const float* __restrict__ dis,
                          const float* __restrict__ b2, const float* __restrict__ Wc,
                          const float* __restrict__ bc, float* __restrict__ out, int n) {
    int i = blockIdx.x * blockDim.x + threadIdx.x;
    if (i >= n) return;
    int p0 = ptr[i], p1 = ptr[i + 1];
    float2 self = *(const float2*)&es[i * 2];
    float a0 = self.x, a1 = self.y;
    for (int p = p0; p < p1; ++p) {
        int r = src[p];
        float2 v = *(const float2*)&es[r * 2];
        a0 += v.x;
        a1 += v.y;
    }
    float d = dis[i];
    float e0 = tanhf(fmaf(a0, d, b2[0]));
    float e1 = tanhf(fmaf(a1, d, b2[1]));
    float z = fmaf(e0, Wc[0], fmaf(e1, Wc[1], bc[0]));
    out[i] = 1.f / (1.f + expf(-z));
}

extern "C" void kernel_launch(void* const* d_in, const int* in_sizes, int n_in,
                              void* d_out, int out_size, void* d_ws, size_t ws_size,
                              hipStream_t stream) {
    const float* x  = (const float*)d_in[0];
    const int*   ei = (const int*)d_in[1];   // [2, E] as int32
    const float* W1 = (const float*)d_in[2];
    const float* b1 = (const float*)d_in[3];
    const float* W2 = (const float*)d_in[4];
    const float* b2 = (const float*)d_in[5];
    const float* Wc = (const float*)d_in[6];
    const float* bc = (const float*)d_in[7];

    const int n = in_sizes[0] / IN_DIM;
    const int E = in_sizes[1] / 2;
    const int* row = ei;
    const int* col = ei + E;

    const int nblk = (n + SCAN_BLK - 1) / SCAN_BLK;

    // workspace layout, 512B-aligned slices
    char* w = (char*)d_ws;
    auto alloc = [&](size_t bytes) {
        char* p = w;
        w += (bytes + 511) & ~(size_t)511;
        return p;
    };
    int*      cnt    = (int*)alloc((size_t)n * 4);
    float*    dis    = (float*)alloc((size_t)n * 4);
    int*      ptr    = (int*)alloc((size_t)(n + 1) * 4);
    int*      cursor = (int*)alloc((size_t)n * 4);
    int*      bsum   = (int*)alloc(128 * 4);
    ushort*   W1p    = (ushort*)alloc(16 * 64 * 8 * 2);
    int*      src    = (int*)alloc((size_t)E * 4);
    _Float16* h1s    = (_Float16*)alloc((size_t)n * HID * 2);
    float*    es     = (float*)alloc((size_t)n * 2 * 4);

    hipMemsetAsync(cnt, 0, (size_t)n * 4, stream);

    k_deg  <<<(E + 255) / 256, 256, 0, stream>>>(col, cnt, E);
    k_dis  <<<(n + 255) / 256, 256, 0, stream>>>(cnt, dis, n);
    k_packW<<<32, 256, 0, stream>>>(W1, W1p);
    k_gemm1<<<(n + 63) / 64, 256, 0, stream>>>(x, W1p, dis, h1s, n);
    k_scanA<<<nblk, SCAN_BLK, 0, stream>>>(cnt, ptr, bsum, n);
    k_scanB<<<1, 128, 0, stream>>>(bsum, nblk);
    k_scanC<<<nblk, SCAN_BLK, 0, stream>>>(ptr, cursor, bsum, n, E);
    k_build<<<(E + 255) / 256, 256, 0, stream>>>(row, col, cursor, src, E);
    k_gather1<<<(n + 3) / 4, 256, 0, stream>>>(ptr, src, h1s, dis, b1, W2, es, n);
    k_gather2<<<(n + 255) / 256, 256, 0, stream>>>(ptr, src, es, dis, b2, Wc, bc,
                                                   (float*)d_out, n);
}

// Round 4
// 312.903 us; speedup vs baseline: 2.2108x; 1.2476x over previous
//
#include <hip/hip_runtime.h>
#include <math.h>

#define IN_DIM 128
#define HID 64
#define SCAN_BLK 1024

typedef __attribute__((ext_vector_type(8))) short bf16x8;
typedef __attribute__((ext_vector_type(4))) float f32x4;
typedef __attribute__((ext_vector_type(4))) _Float16 f16x4;

static __device__ inline short f2bf(float f) {
    unsigned u = __float_as_uint(f);
    u += 0x7fff + ((u >> 16) & 1);          // RNE
    return (short)(u >> 16);
}

// ---------------- degree count (indegree over col) -----------------------
__global__ void k_deg(const int* __restrict__ col, int* __restrict__ cnt, int E) {
    int e = blockIdx.x * blockDim.x + threadIdx.x;
    if (e < E) atomicAdd(&cnt[col[e]], 1);
}

__global__ void k_dis(const int* __restrict__ cnt, float* __restrict__ dis, int n) {
    int i = blockIdx.x * blockDim.x + threadIdx.x;
    if (i < n) dis[i] = rsqrtf((float)(cnt[i] + 1));
}

// ------- pack W1 [128][64] f32 -> bf16 MFMA B-fragment order -------------
__global__ void k_packW(const float* __restrict__ W1, ushort* __restrict__ W1p) {
    int idx = blockIdx.x * 256 + threadIdx.x;        // 0..8191
    int i = idx & 7, lane = (idx >> 3) & 63, fb = (idx >> 9) & 3, kc = (idx >> 11) & 3;
    int k = kc * 32 + (lane >> 4) * 8 + i;
    int f = fb * 16 + (lane & 15);
    W1p[idx] = (ushort)f2bf(W1[k * HID + f]);
}

// ---------------- 3-phase exclusive scan of cnt -> ptr -------------------
__global__ void __launch_bounds__(SCAN_BLK) k_scanA(const int* __restrict__ cnt,
                                                    int* __restrict__ ptr,
                                                    int* __restrict__ bsum, int n) {
    __shared__ int s[SCAN_BLK];
    int tid = threadIdx.x;
    int i = blockIdx.x * SCAN_BLK + tid;
    int v = (i < n) ? cnt[i] : 0;
    s[tid] = v;
    __syncthreads();
    for (int off = 1; off < SCAN_BLK; off <<= 1) {
        int t = (tid >= off) ? s[tid - off] : 0;
        __syncthreads();
        s[tid] += t;
        __syncthreads();
    }
    if (i < n) ptr[i] = s[tid] - v;
    if (tid == SCAN_BLK - 1) bsum[blockIdx.x] = s[tid];
}

__global__ void k_scanB(int* __restrict__ bsum, int nb) {
    __shared__ int s[128];
    int tid = threadIdx.x;
    int v = (tid < nb) ? bsum[tid] : 0;
    s[tid] = v;
    __syncthreads();
    for (int off = 1; off < 128; off <<= 1) {
        int t = (tid >= off) ? s[tid - off] : 0;
        __syncthreads();
        s[tid] += t;
        __syncthreads();
    }
    if (tid < nb) bsum[tid] = s[tid] - v;
}

__global__ void __launch_bounds__(SCAN_BLK) k_scanC(int* __restrict__ ptr,
                                                    int* __restrict__ cursor,
                                                    const int* __restrict__ bsum,
                                                    int n, int E) {
    int i = blockIdx.x * SCAN_BLK + threadIdx.x;
    if (i < n) {
        int p = ptr[i] + bsum[blockIdx.x];
        ptr[i] = p;
        cursor[i] = p;
        if (i == n - 1) ptr[n] = E;
    }
}

// ---------------- CSR position-scatter: src only -------------------------
__global__ void k_build(const int* __restrict__ row, const int* __restrict__ col,
                        int* __restrict__ cursor, int* __restrict__ src, int E) {
    int e = blockIdx.x * blockDim.x + threadIdx.x;
    if (e >= E) return;
    int r = row[e], c = col[e];
    int p = atomicAdd(&cursor[c], 1);
    src[p] = r;
}

// ------- h1s = (x @ W1) * dis[node]  via bf16 MFMA, fp16 output ----------
__global__ void __launch_bounds__(256) k_gemm1(const float* __restrict__ x,
                                               const ushort* __restrict__ W1p,
                                               const float* __restrict__ dis,
                                               _Float16* __restrict__ h1s, int n) {
    int t = threadIdx.x, wave = t >> 6, lane = t & 63;
    int nb = blockIdx.x * 64 + wave * 16;
    int arow = nb + (lane & 15);            // A: row = lane&15
    int g = lane >> 4;                      // k-group
    const bf16x8* Wp = (const bf16x8*)W1p;

    f32x4 acc0 = {0.f, 0.f, 0.f, 0.f}, acc1 = acc0, acc2 = acc0, acc3 = acc0;

#pragma unroll
    for (int kc = 0; kc < 4; ++kc) {
        bf16x8 a;
        if (arow < n) {
            const float4* xp = (const float4*)(x + (size_t)arow * IN_DIM + kc * 32 + g * 8);
            float4 x0 = xp[0], x1 = xp[1];
            a[0] = f2bf(x0.x); a[1] = f2bf(x0.y); a[2] = f2bf(x0.z); a[3] = f2bf(x0.w);
            a[4] = f2bf(x1.x); a[5] = f2bf(x1.y); a[6] = f2bf(x1.z); a[7] = f2bf(x1.w);
        } else {
            for (int i = 0; i < 8; ++i) a[i] = 0;
        }
        acc0 = __builtin_amdgcn_mfma_f32_16x16x32_bf16(a, Wp[(kc * 4 + 0) * 64 + lane], acc0, 0, 0, 0);
        acc1 = __builtin_amdgcn_mfma_f32_16x16x32_bf16(a, Wp[(kc * 4 + 1) * 64 + lane], acc1, 0, 0, 0);
        acc2 = __builtin_amdgcn_mfma_f32_16x16x32_bf16(a, Wp[(kc * 4 + 2) * 64 + lane], acc2, 0, 0, 0);
        acc3 = __builtin_amdgcn_mfma_f32_16x16x32_bf16(a, Wp[(kc * 4 + 3) * 64 + lane], acc3, 0, 0, 0);
    }

    // D: col = lane&15, row = (lane>>4)*4 + reg
    int c = lane & 15, rbase = g * 4;
    float dn[4];
    int nd[4];
#pragma unroll
    for (int r = 0; r < 4; ++r) {
        nd[r] = nb + rbase + r;
        dn[r] = (nd[r] < n) ? dis[nd[r]] : 0.f;
    }
#define EPI(FB, ACC)                                                          \
    {                                                                         \
        int f = FB * 16 + c;                                                  \
        _Pragma("unroll") for (int r = 0; r < 4; ++r) {                       \
            if (nd[r] < n)                                                    \
                h1s[(size_t)nd[r] * HID + f] = (_Float16)(ACC[r] * dn[r]);    \
        }                                                                     \
    }
    EPI(0, acc0) EPI(1, acc1) EPI(2, acc2) EPI(3, acc3)
#undef EPI
}

// ---- gather layer-1: 4x16-lane groups, 8B/lane, 4 independent chains ----
// agg = dis_c*(sum_r h1s[r] + h1s[c]); tanh; @W2; es = result * dis_c
__global__ void __launch_bounds__(256) k_gather1(const int* __restrict__ ptr,
                                                 const int* __restrict__ src,
                                                 const _Float16* __restrict__ h1s,
                                                 const float* __restrict__ dis,
                                                 const float* __restrict__ b1,
                                                 const float* __restrict__ W2,
                                                 float* __restrict__ es, int n) {
    int t = threadIdx.x, wave = t >> 6, lane = t & 63;
    int node = blockIdx.x * 4 + wave;
    if (node >= n) return;
    int grp = lane >> 4;             // 0..3: edge-strided group
    int sub = lane & 15;             // feature slice: features sub*4 .. sub*4+3
    int p0 = ptr[node], p1 = ptr[node + 1];

    float a0 = 0.f, a1 = 0.f, a2 = 0.f, a3 = 0.f;
    if (grp == 0) {                  // self-loop, counted once
        f16x4 v = *(const f16x4*)(h1s + (size_t)node * HID + sub * 4);
        a0 = (float)v[0]; a1 = (float)v[1]; a2 = (float)v[2]; a3 = (float)v[3];
    }
    for (int p = p0 + grp; p < p1; p += 4) {
        int r = src[p];
        f16x4 v = *(const f16x4*)(h1s + (size_t)r * HID + sub * 4);
        a0 += (float)v[0]; a1 += (float)v[1]; a2 += (float)v[2]; a3 += (float)v[3];
    }
    // merge the 4 groups (features identical across groups)
    a0 += __shfl_xor(a0, 16); a0 += __shfl_xor(a0, 32);
    a1 += __shfl_xor(a1, 16); a1 += __shfl_xor(a1, 32);
    a2 += __shfl_xor(a2, 16); a2 += __shfl_xor(a2, 32);
    a3 += __shfl_xor(a3, 16); a3 += __shfl_xor(a3, 32);

    float d = dis[node];
    float4 bb = *(const float4*)(b1 + sub * 4);
    float v0 = tanhf(fmaf(a0, d, bb.x));
    float v1 = tanhf(fmaf(a1, d, bb.y));
    float v2 = tanhf(fmaf(a2, d, bb.z));
    float v3 = tanhf(fmaf(a3, d, bb.w));

    float4 w01 = *(const float4*)(W2 + sub * 8);      // W2 rows sub*4, sub*4+1
    float4 w23 = *(const float4*)(W2 + sub * 8 + 4);  // rows sub*4+2, sub*4+3
    float s0 = v0 * w01.x + v1 * w01.z + v2 * w23.x + v3 * w23.z;
    float s1 = v0 * w01.y + v1 * w01.w + v2 * w23.y + v3 * w23.w;
    s0 += __shfl_xor(s0, 1); s1 += __shfl_xor(s1, 1);
    s0 += __shfl_xor(s0, 2); s1 += __shfl_xor(s1, 2);
    s0 += __shfl_xor(s0, 4); s1 += __shfl_xor(s1, 4);
    s0 += __shfl_xor(s0, 8); s1 += __shfl_xor(s1, 8);
    if (lane == 0) {
        es[node * 2 + 0] = s0 * d;   // pre-scaled by dis for layer-2 gather
        es[node * 2 + 1] = s1 * d;
    }
}

// ---- gather layer-2 + tanh + classifier + sigmoid -----------------------
__global__ void k_gather2(const int* __restrict__ ptr, const int* __restrict__ src,
                          const float* __restrict__ es, const float* __restrict__ dis,
                          const float* __restrict__ b2, const float* __restrict__ Wc,
                          const float* __restrict__ bc, float* __restrict__ out, int n) {
    int i = blockIdx.x * blockDim.x + threadIdx.x;
    if (i >= n) return;
    int p0 = ptr[i], p1 = ptr[i + 1];
    float2 self = *(const float2*)&es[i * 2];
    float a0 = self.x, a1 = self.y;
    for (int p = p0; p < p1; ++p) {
        int r = src[p];
        float2 v = *(const float2*)&es[r * 2];
        a0 += v.x;
        a1 += v.y;
    }
    float d = dis[i];
    float e0 = tanhf(fmaf(a0, d, b2[0]));
    float e1 = tanhf(fmaf(a1, d, b2[1]));
    float z = fmaf(e0, Wc[0], fmaf(e1, Wc[1], bc[0]));
    out[i] = 1.f / (1.f + expf(-z));
}

extern "C" void kernel_launch(void* const* d_in, const int* in_sizes, int n_in,
                              void* d_out, int out_size, void* d_ws, size_t ws_size,
                              hipStream_t stream) {
    const float* x  = (const float*)d_in[0];
    const int*   ei = (const int*)d_in[1];   // [2, E] as int32
    const float* W1 = (const float*)d_in[2];
    const float* b1 = (const float*)d_in[3];
    const float* W2 = (const float*)d_in[4];
    const float* b2 = (const float*)d_in[5];
    const float* Wc = (const float*)d_in[6];
    const float* bc = (const float*)d_in[7];

    const int n = in_sizes[0] / IN_DIM;
    const int E = in_sizes[1] / 2;
    const int* row = ei;
    const int* col = ei + E;

    const int nblk = (n + SCAN_BLK - 1) / SCAN_BLK;

    // workspace layout, 512B-aligned slices
    char* w = (char*)d_ws;
    auto alloc = [&](size_t bytes) {
        char* p = w;
        w += (bytes + 511) & ~(size_t)511;
        return p;
    };
    int*      cnt    = (int*)alloc((size_t)n * 4);
    float*    dis    = (float*)alloc((size_t)n * 4);
    int*      ptr    = (int*)alloc((size_t)(n + 1) * 4);
    int*      cursor = (int*)alloc((size_t)n * 4);
    int*      bsum   = (int*)alloc(128 * 4);
    ushort*   W1p    = (ushort*)alloc(16 * 64 * 8 * 2);
    int*      src    = (int*)alloc((size_t)E * 4);
    _Float16* h1s    = (_Float16*)alloc((size_t)n * HID * 2);
    float*    es     = (float*)alloc((size_t)n * 2 * 4);

    hipMemsetAsync(cnt, 0, (size_t)n * 4, stream);

    k_deg  <<<(E + 255) / 256, 256, 0, stream>>>(col, cnt, E);
    k_dis  <<<(n + 255) / 256, 256, 0, stream>>>(cnt, dis, n);
    k_packW<<<32, 256, 0, stream>>>(W1, W1p);
    k_gemm1<<<(n + 63) / 64, 256, 0, stream>>>(x, W1p, dis, h1s, n);
    k_scanA<<<nblk, SCAN_BLK, 0, stream>>>(cnt, ptr, bsum, n);
    k_scanB<<<1, 128, 0, stream>>>(bsum, nblk);
    k_scanC<<<nblk, SCAN_BLK, 0, stream>>>(ptr, cursor, bsum, n, E);
    k_build<<<(E + 255) / 256, 256, 0, stream>>>(row, col, cursor, src, E);
    k_gather1<<<(n + 3) / 4, 256, 0, stream>>>(ptr, src, h1s, dis, b1, W2, es, n);
    k_gather2<<<(n + 255) / 256, 256, 0, stream>>>(ptr, src, es, dis, b2, Wc, bc,
                                                   (float*)d_out, n);
}